// Round 1
// baseline (680.708 us; speedup 1.0000x reference)
//
#include <hip/hip_runtime.h>

typedef float  f32x4  __attribute__((ext_vector_type(4)));
typedef __bf16 bf16x4 __attribute__((ext_vector_type(4)));
typedef __bf16 bf16x8 __attribute__((ext_vector_type(8)));

#define MFMA16(a, b, c) __builtin_amdgcn_mfma_f32_16x16x32_bf16((a), (b), (c), 0, 0, 0)

constexpr int EMB  = 1024;
constexpr int NSEQ = 2048;
constexpr int NB   = 4;
constexpr int NH   = 16;
constexpr int DH   = 64;
constexpr size_t HSTRIDE = (size_t)NSEQ * DH;    // elements per head (Q/K/V)
constexpr size_t MAT     = (size_t)NB * NSEQ * EMB;  // 8388608

__device__ __forceinline__ __bf16 f2bf(float f) {
  unsigned u = __builtin_bit_cast(unsigned, f);
  u += 0x7fffu + ((u >> 16) & 1u);               // round-to-nearest-even
  unsigned short h = (unsigned short)(u >> 16);
  return __builtin_bit_cast(__bf16, h);
}

__device__ __forceinline__ bf16x8 lds_frag(const __bf16* base, int row, int koff, int stride) {
  const __bf16* p = base + row * stride + koff;
  bf16x4 lo = *reinterpret_cast<const bf16x4*>(p);
  bf16x4 hi = *reinterpret_cast<const bf16x4*>(p + 4);
  return __builtin_shufflevector(lo, hi, 0, 1, 2, 3, 4, 5, 6, 7);
}

// ---------------- GEMM core: C[m,n] = sum_k A[m,k] * W[n,k] + bias[n] ----------------
// MODE 0: fp32 out, row-major [M][EMB]
// MODE 1: bf16 out, layout [b][h][n][d]   (Q, K)
// MODE 2: bf16 out, layout [b][h][d][n]   (V transposed)
template <int MODE>
__device__ __forceinline__ void gemm_core(__bf16* Al, __bf16* Bl,
                                          const float* __restrict__ A,
                                          const float* __restrict__ W,
                                          const float* __restrict__ bias,
                                          float* __restrict__ outF,
                                          __bf16* __restrict__ outB) {
  const int t = threadIdx.x;
  const int lane = t & 63, wid = t >> 6;
  const int wr = wid >> 1, wc = wid & 1;
  const int m0 = blockIdx.y * 128, n0 = blockIdx.x * 128;
  const int l15 = lane & 15, g = lane >> 4;

  f32x4 acc[4][4];
#pragma unroll
  for (int i = 0; i < 4; ++i)
#pragma unroll
    for (int j = 0; j < 4; ++j) acc[i][j] = f32x4{0.f, 0.f, 0.f, 0.f};

#pragma unroll 1
  for (int k0 = 0; k0 < EMB; k0 += 32) {
#pragma unroll
    for (int jj = 0; jj < 4; ++jj) {
      int f = t + jj * 256;
      int row = f >> 3, kq = f & 7;            // 128 rows x 8 float4 = 128x32 tile
      f32x4 a4 = *reinterpret_cast<const f32x4*>(A + (size_t)(m0 + row) * EMB + k0 + kq * 4);
      f32x4 b4 = *reinterpret_cast<const f32x4*>(W + (size_t)(n0 + row) * EMB + k0 + kq * 4);
      bf16x4 av  = {f2bf(a4[0]), f2bf(a4[1]), f2bf(a4[2]), f2bf(a4[3])};
      bf16x4 bv4 = {f2bf(b4[0]), f2bf(b4[1]), f2bf(b4[2]), f2bf(b4[3])};
      *reinterpret_cast<bf16x4*>(Al + row * 40 + kq * 4) = av;   // stride 40 pads banks
      *reinterpret_cast<bf16x4*>(Bl + row * 40 + kq * 4) = bv4;
    }
    __syncthreads();
    bf16x8 af[4], bfr[4];
#pragma unroll
    for (int i = 0; i < 4; ++i) af[i]  = lds_frag(Al, wr * 64 + i * 16 + l15, g * 8, 40);
#pragma unroll
    for (int i = 0; i < 4; ++i) bfr[i] = lds_frag(Bl, wc * 64 + i * 16 + l15, g * 8, 40);
#pragma unroll
    for (int mi = 0; mi < 4; ++mi)
#pragma unroll
      for (int ni = 0; ni < 4; ++ni)
        acc[mi][ni] = MFMA16(af[mi], bfr[ni], acc[mi][ni]);
    __syncthreads();
  }

#pragma unroll
  for (int mi = 0; mi < 4; ++mi)
#pragma unroll
    for (int ni = 0; ni < 4; ++ni)
#pragma unroll
      for (int j = 0; j < 4; ++j) {
        int rg = m0 + wr * 64 + mi * 16 + g * 4 + j;   // C/D: row=(lane>>4)*4+reg
        int cg = n0 + wc * 64 + ni * 16 + l15;         //      col=lane&15
        float v = acc[mi][ni][j] + bias[cg];
        if constexpr (MODE == 0) {
          outF[(size_t)rg * EMB + cg] = v;
        } else {
          int bb = rg >> 11, r = rg & (NSEQ - 1);
          int hh = cg >> 6,  d = cg & (DH - 1);
          size_t hb = (size_t)(bb * NH + hh);
          if constexpr (MODE == 1)
            outB[(hb * NSEQ + r) * DH + d] = f2bf(v);
          else
            outB[(hb * DH + d) * NSEQ + r] = f2bf(v);
        }
      }
}

__global__ __launch_bounds__(256) void qkv_kernel(const float* __restrict__ x,
    const float* __restrict__ Wq, const float* __restrict__ bq,
    const float* __restrict__ Wk, const float* __restrict__ bk,
    const float* __restrict__ Wv, const float* __restrict__ bv,
    __bf16* __restrict__ ws) {
  __shared__ __align__(16) __bf16 smem[2 * 128 * 40];
  __bf16* Al = smem;
  __bf16* Bl = smem + 128 * 40;
  int z = blockIdx.z;
  if (z == 0)      gemm_core<1>(Al, Bl, x, Wq, bq, nullptr, ws);
  else if (z == 1) gemm_core<1>(Al, Bl, x, Wk, bk, nullptr, ws + MAT);
  else             gemm_core<2>(Al, Bl, x, Wv, bv, nullptr, ws + 2 * MAT);
}

__global__ __launch_bounds__(256) void oproj_kernel(const float* __restrict__ attnw,
    const float* __restrict__ Wo, const float* __restrict__ bo,
    float* __restrict__ outp) {
  __shared__ __align__(16) __bf16 smem[2 * 128 * 40];
  gemm_core<0>(smem, smem + 128 * 40, attnw, Wo, bo, outp, nullptr);
}

// ---------------- Flash attention: block = 64 q rows (4 waves x 16), KV tiles of 64 ----------------
__global__ __launch_bounds__(256) void flash_kernel(const __bf16* __restrict__ Qb,
                                                    const __bf16* __restrict__ Kb,
                                                    const __bf16* __restrict__ Vtb,
                                                    float* __restrict__ attnw) {
  __shared__ __align__(16) __bf16 P[4 * 16 * 68];   // per-wave 16x68 P tile (bf16)
  const int t = threadIdx.x;
  const int lane = t & 63, w = t >> 6;
  const int l15 = lane & 15, g = lane >> 4;
  const int h = blockIdx.y, b = blockIdx.z;
  const size_t hoff = ((size_t)(b * NH + h)) * HSTRIDE;
  const __bf16* Qh = Qb + hoff;          // [2048][64]
  const __bf16* Kh = Kb + hoff;          // [2048][64]
  const __bf16* Vh = Vtb + hoff;         // [64][2048]  (transposed)
  const int q0 = blockIdx.x * 64 + w * 16;

  // Q fragments hoisted to registers (constant over kv loop)
  bf16x8 aq0 = *reinterpret_cast<const bf16x8*>(Qh + (size_t)(q0 + l15) * DH + g * 8);
  bf16x8 aq1 = *reinterpret_cast<const bf16x8*>(Qh + (size_t)(q0 + l15) * DH + 32 + g * 8);

  f32x4 o[4];
  float mrow[4], lrow[4];
#pragma unroll
  for (int i = 0; i < 4; ++i) { o[i] = f32x4{0.f, 0.f, 0.f, 0.f}; mrow[i] = -1e30f; lrow[i] = 0.f; }

  __bf16* Pw = P + w * 16 * 68;

#pragma unroll 1
  for (int kt = 0; kt < NSEQ; kt += 64) {
    // S = (Q K^T): A=Q frag, B=K rows read directly from global (L2/L3-resident)
    f32x4 s[4];
#pragma unroll
    for (int ni = 0; ni < 4; ++ni) {
      const __bf16* kp = Kh + (size_t)(kt + ni * 16 + l15) * DH + g * 8;
      bf16x8 kf0 = *reinterpret_cast<const bf16x8*>(kp);
      bf16x8 kf1 = *reinterpret_cast<const bf16x8*>(kp + 32);
      f32x4 z = f32x4{0.f, 0.f, 0.f, 0.f};
      z = MFMA16(aq0, kf0, z);
      z = MFMA16(aq1, kf1, z);
      s[ni] = z;
    }
    // online softmax; rows live on 16-lane groups -> shfl_xor reduce over low 4 bits
#pragma unroll
    for (int j = 0; j < 4; ++j) {
      float v0 = s[0][j] * 0.125f, v1 = s[1][j] * 0.125f;
      float v2 = s[2][j] * 0.125f, v3 = s[3][j] * 0.125f;
      float mx = fmaxf(fmaxf(v0, v1), fmaxf(v2, v3));
      mx = fmaxf(mx, __shfl_xor(mx, 1));
      mx = fmaxf(mx, __shfl_xor(mx, 2));
      mx = fmaxf(mx, __shfl_xor(mx, 4));
      mx = fmaxf(mx, __shfl_xor(mx, 8));
      float mn = fmaxf(mrow[j], mx);
      float corr = __expf(mrow[j] - mn);
      mrow[j] = mn;
      float p0 = __expf(v0 - mn), p1 = __expf(v1 - mn);
      float p2 = __expf(v2 - mn), p3 = __expf(v3 - mn);
      float ps = p0 + p1 + p2 + p3;
      ps += __shfl_xor(ps, 1);
      ps += __shfl_xor(ps, 2);
      ps += __shfl_xor(ps, 4);
      ps += __shfl_xor(ps, 8);
      lrow[j] = lrow[j] * corr + ps;
      o[0][j] *= corr; o[1][j] *= corr; o[2][j] *= corr; o[3][j] *= corr;
      int prow = g * 4 + j;
      Pw[prow * 68 +  0 + l15] = f2bf(p0);
      Pw[prow * 68 + 16 + l15] = f2bf(p1);
      Pw[prow * 68 + 32 + l15] = f2bf(p2);
      Pw[prow * 68 + 48 + l15] = f2bf(p3);
    }
    __syncthreads();
    // PV: A=P (from LDS, A-frag layout), B=V^T rows direct from global
    bf16x8 ap0 = lds_frag(Pw, l15, g * 8, 68);
    bf16x8 ap1 = lds_frag(Pw, l15, 32 + g * 8, 68);
#pragma unroll
    for (int ni = 0; ni < 4; ++ni) {
      const __bf16* vp = Vh + (size_t)(ni * 16 + l15) * NSEQ + kt + g * 8;
      bf16x8 vf0 = *reinterpret_cast<const bf16x8*>(vp);
      bf16x8 vf1 = *reinterpret_cast<const bf16x8*>(vp + 32);
      o[ni] = MFMA16(ap0, vf0, o[ni]);
      o[ni] = MFMA16(ap1, vf1, o[ni]);
    }
    __syncthreads();
  }

#pragma unroll
  for (int ni = 0; ni < 4; ++ni)
#pragma unroll
    for (int j = 0; j < 4; ++j) {
      int row = q0 + g * 4 + j;
      int col = h * DH + ni * 16 + l15;
      attnw[((size_t)(b * NSEQ + row)) * EMB + col] = o[ni][j] / lrow[j];
    }
}

extern "C" void kernel_launch(void* const* d_in, const int* in_sizes, int n_in,
                              void* d_out, int out_size, void* d_ws, size_t ws_size,
                              hipStream_t stream) {
  const float* q  = (const float*)d_in[0];
  const float* Wq = (const float*)d_in[1];
  const float* bq = (const float*)d_in[2];
  const float* Wk = (const float*)d_in[3];
  const float* bk = (const float*)d_in[4];
  const float* Wv = (const float*)d_in[5];
  const float* bv = (const float*)d_in[6];
  const float* Wo = (const float*)d_in[7];
  const float* bo = (const float*)d_in[8];

  float* outp  = (float*)d_out;
  float* attnw = outp + MAT;          // second tuple element
  __bf16* ws   = (__bf16*)d_ws;       // Q | K | V^T  bf16, 3*MAT elements

  dim3 blk(256);
  qkv_kernel<<<dim3(8, 64, 3), blk, 0, stream>>>(q, Wq, bq, Wk, bk, Wv, bv, ws);
  flash_kernel<<<dim3(NSEQ / 64, NH, NB), blk, 0, stream>>>(ws, ws + MAT, ws + 2 * MAT, attnw);
  oproj_kernel<<<dim3(8, 64, 1), blk, 0, stream>>>(attnw, Wo, bo, outp);
}

// Round 2
// 423.561 us; speedup vs baseline: 1.6071x; 1.6071x over previous
//
#include <hip/hip_runtime.h>

typedef float  f32x4  __attribute__((ext_vector_type(4)));
typedef __bf16 bf16x4 __attribute__((ext_vector_type(4)));
typedef __bf16 bf16x8 __attribute__((ext_vector_type(8)));

#define MFMA16(a, b, c) __builtin_amdgcn_mfma_f32_16x16x32_bf16((a), (b), (c), 0, 0, 0)

constexpr int EMB  = 1024;
constexpr int NSEQ = 2048;
constexpr int NB   = 4;
constexpr int NH   = 16;
constexpr int DH   = 64;
constexpr size_t HSTRIDE = (size_t)NSEQ * DH;    // elements per head (Q/K/V)
constexpr size_t MAT     = (size_t)NB * NSEQ * EMB;  // 8388608

__device__ __forceinline__ __bf16 f2bf(float f) {
  unsigned u = __builtin_bit_cast(unsigned, f);
  u += 0x7fffu + ((u >> 16) & 1u);               // round-to-nearest-even
  unsigned short h = (unsigned short)(u >> 16);
  return __builtin_bit_cast(__bf16, h);
}

__device__ __forceinline__ bf16x8 lds_frag(const __bf16* base, int row, int koff, int stride) {
  const __bf16* p = base + row * stride + koff;
  bf16x4 lo = *reinterpret_cast<const bf16x4*>(p);
  bf16x4 hi = *reinterpret_cast<const bf16x4*>(p + 4);
  return __builtin_shufflevector(lo, hi, 0, 1, 2, 3, 4, 5, 6, 7);
}

// ---------------- GEMM core: C[m,n] = sum_k A[m,k] * W[n,k] + bias[n] ----------------
// MODE 0: fp32 out, row-major [M][EMB]
// MODE 1: bf16 out, layout [b][h][n][d]   (Q, K)
// MODE 2: bf16 out, layout [b][h][d][n]   (V transposed)
template <int MODE>
__device__ __forceinline__ void gemm_core(__bf16* Al, __bf16* Bl,
                                          const float* __restrict__ A,
                                          const float* __restrict__ W,
                                          const float* __restrict__ bias,
                                          float* __restrict__ outF,
                                          __bf16* __restrict__ outB) {
  const int t = threadIdx.x;
  const int lane = t & 63, wid = t >> 6;
  const int wr = wid >> 1, wc = wid & 1;
  const int m0 = blockIdx.y * 128, n0 = blockIdx.x * 128;
  const int l15 = lane & 15, g = lane >> 4;

  f32x4 acc[4][4];
#pragma unroll
  for (int i = 0; i < 4; ++i)
#pragma unroll
    for (int j = 0; j < 4; ++j) acc[i][j] = f32x4{0.f, 0.f, 0.f, 0.f};

#pragma unroll 1
  for (int k0 = 0; k0 < EMB; k0 += 32) {
#pragma unroll
    for (int jj = 0; jj < 4; ++jj) {
      int f = t + jj * 256;
      int row = f >> 3, kq = f & 7;            // 128 rows x 8 float4 = 128x32 tile
      f32x4 a4 = *reinterpret_cast<const f32x4*>(A + (size_t)(m0 + row) * EMB + k0 + kq * 4);
      f32x4 b4 = *reinterpret_cast<const f32x4*>(W + (size_t)(n0 + row) * EMB + k0 + kq * 4);
      bf16x4 av  = {f2bf(a4[0]), f2bf(a4[1]), f2bf(a4[2]), f2bf(a4[3])};
      bf16x4 bv4 = {f2bf(b4[0]), f2bf(b4[1]), f2bf(b4[2]), f2bf(b4[3])};
      *reinterpret_cast<bf16x4*>(Al + row * 40 + kq * 4) = av;   // stride 40 pads banks
      *reinterpret_cast<bf16x4*>(Bl + row * 40 + kq * 4) = bv4;
    }
    __syncthreads();
    bf16x8 af[4], bfr[4];
#pragma unroll
    for (int i = 0; i < 4; ++i) af[i]  = lds_frag(Al, wr * 64 + i * 16 + l15, g * 8, 40);
#pragma unroll
    for (int i = 0; i < 4; ++i) bfr[i] = lds_frag(Bl, wc * 64 + i * 16 + l15, g * 8, 40);
#pragma unroll
    for (int mi = 0; mi < 4; ++mi)
#pragma unroll
      for (int ni = 0; ni < 4; ++ni)
        acc[mi][ni] = MFMA16(af[mi], bfr[ni], acc[mi][ni]);
    __syncthreads();
  }

#pragma unroll
  for (int mi = 0; mi < 4; ++mi)
#pragma unroll
    for (int ni = 0; ni < 4; ++ni)
#pragma unroll
      for (int j = 0; j < 4; ++j) {
        int rg = m0 + wr * 64 + mi * 16 + g * 4 + j;   // C/D: row=(lane>>4)*4+reg
        int cg = n0 + wc * 64 + ni * 16 + l15;         //      col=lane&15
        float v = acc[mi][ni][j] + bias[cg];
        if constexpr (MODE == 0) {
          outF[(size_t)rg * EMB + cg] = v;
        } else {
          int bb = rg >> 11, r = rg & (NSEQ - 1);
          int hh = cg >> 6,  d = cg & (DH - 1);
          size_t hb = (size_t)(bb * NH + hh);
          if constexpr (MODE == 1)
            outB[(hb * NSEQ + r) * DH + d] = f2bf(v);
          else
            outB[(hb * DH + d) * NSEQ + r] = f2bf(v);
        }
      }
}

__global__ __launch_bounds__(256) void qkv_kernel(const float* __restrict__ x,
    const float* __restrict__ Wq, const float* __restrict__ bq,
    const float* __restrict__ Wk, const float* __restrict__ bk,
    const float* __restrict__ Wv, const float* __restrict__ bv,
    __bf16* __restrict__ ws) {
  __shared__ __align__(16) __bf16 smem[2 * 128 * 40];
  __bf16* Al = smem;
  __bf16* Bl = smem + 128 * 40;
  int z = blockIdx.z;
  if (z == 0)      gemm_core<1>(Al, Bl, x, Wq, bq, nullptr, ws);
  else if (z == 1) gemm_core<1>(Al, Bl, x, Wk, bk, nullptr, ws + MAT);
  else             gemm_core<2>(Al, Bl, x, Wv, bv, nullptr, ws + 2 * MAT);
}

__global__ __launch_bounds__(256) void oproj_kernel(const float* __restrict__ attnw,
    const float* __restrict__ Wo, const float* __restrict__ bo,
    float* __restrict__ outp) {
  __shared__ __align__(16) __bf16 smem[2 * 128 * 40];
  gemm_core<0>(smem, smem + 128 * 40, attnw, Wo, bo, outp, nullptr);
}

// ---------------- Flash attention ----------------
// Block = 128 q rows (4 waves x 32 rows). KV tiles of 64.
// No __syncthreads: each wave owns a private P slice of LDS; intra-wave
// ds_write->ds_read ordering is enforced by compiler lgkmcnt.
// Pipeline: V(kt) loads issue at top (consumed at bottom of iter);
// K(kt+64) loads issue before softmax (consumed next iter).
__global__ __launch_bounds__(256) void flash_kernel(const __bf16* __restrict__ Qb,
                                                    const __bf16* __restrict__ Kb,
                                                    const __bf16* __restrict__ Vtb,
                                                    float* __restrict__ attnw) {
  __shared__ __align__(16) __bf16 P[4 * 32 * 68];   // per-wave 32x68 P tile (bf16)
  const int t = threadIdx.x;
  const int lane = t & 63, w = t >> 6;
  const int l15 = lane & 15, g = lane >> 4;
  const int h = blockIdx.y, b = blockIdx.z;
  const size_t hoff = ((size_t)(b * NH + h)) * HSTRIDE;
  const __bf16* Qh = Qb + hoff;          // [2048][64]
  const __bf16* Kh = Kb + hoff;          // [2048][64]
  const __bf16* Vh = Vtb + hoff;         // [64][2048]  (transposed)
  const int q0 = blockIdx.x * 128 + w * 32;

  // Q fragments hoisted to registers (constant over kv loop): 2 row-blocks x 2 k-splits
  bf16x8 aq[2][2];
#pragma unroll
  for (int r = 0; r < 2; ++r)
#pragma unroll
    for (int ks = 0; ks < 2; ++ks)
      aq[r][ks] = *reinterpret_cast<const bf16x8*>(
          Qh + (size_t)(q0 + r * 16 + l15) * DH + ks * 32 + g * 8);

  f32x4 o[2][4];
  float mrow[2][4], lrow[2][4];
#pragma unroll
  for (int r = 0; r < 2; ++r)
#pragma unroll
    for (int i = 0; i < 4; ++i) {
      o[r][i] = f32x4{0.f, 0.f, 0.f, 0.f};
      mrow[r][i] = -1e30f;
      lrow[r][i] = 0.f;
    }

  __bf16* Pw = P + w * 32 * 68;

  // prologue: K fragments for tile 0
  bf16x8 kf[4][2];
#pragma unroll
  for (int n = 0; n < 4; ++n)
#pragma unroll
    for (int ks = 0; ks < 2; ++ks)
      kf[n][ks] = *reinterpret_cast<const bf16x8*>(
          Kh + (size_t)(n * 16 + l15) * DH + ks * 32 + g * 8);

#pragma unroll 1
  for (int kt = 0; kt < NSEQ; kt += 64) {
    // issue V loads for this tile (consumed by PV at the bottom)
    bf16x8 vf[4][2];
#pragma unroll
    for (int n = 0; n < 4; ++n)
#pragma unroll
      for (int ks = 0; ks < 2; ++ks)
        vf[n][ks] = *reinterpret_cast<const bf16x8*>(
            Vh + (size_t)(n * 16 + l15) * NSEQ + kt + ks * 32 + g * 8);

    // S = Q K^T  (2 row-blocks x 4 n-blocks, K=64)
    f32x4 s[2][4];
#pragma unroll
    for (int r = 0; r < 2; ++r)
#pragma unroll
      for (int n = 0; n < 4; ++n) {
        f32x4 z = f32x4{0.f, 0.f, 0.f, 0.f};
        z = MFMA16(aq[r][0], kf[n][0], z);
        z = MFMA16(aq[r][1], kf[n][1], z);
        s[r][n] = z;
      }

    // issue next tile's K loads (consumed next iteration)
    int ktn = (kt + 64 < NSEQ) ? kt + 64 : 0;   // clamp: last prefetch is dead
    bf16x8 kn[4][2];
#pragma unroll
    for (int n = 0; n < 4; ++n)
#pragma unroll
      for (int ks = 0; ks < 2; ++ks)
        kn[n][ks] = *reinterpret_cast<const bf16x8*>(
            Kh + (size_t)(ktn + n * 16 + l15) * DH + ks * 32 + g * 8);

    // online softmax; each 16-lane group holds 4 rows (j), cols on l15
#pragma unroll
    for (int r = 0; r < 2; ++r)
#pragma unroll
      for (int j = 0; j < 4; ++j) {
        float v0 = s[r][0][j] * 0.125f, v1 = s[r][1][j] * 0.125f;
        float v2 = s[r][2][j] * 0.125f, v3 = s[r][3][j] * 0.125f;
        float mx = fmaxf(fmaxf(v0, v1), fmaxf(v2, v3));
        mx = fmaxf(mx, __shfl_xor(mx, 1));
        mx = fmaxf(mx, __shfl_xor(mx, 2));
        mx = fmaxf(mx, __shfl_xor(mx, 4));
        mx = fmaxf(mx, __shfl_xor(mx, 8));
        float mn = fmaxf(mrow[r][j], mx);
        float corr = __expf(mrow[r][j] - mn);
        mrow[r][j] = mn;
        float p0 = __expf(v0 - mn), p1 = __expf(v1 - mn);
        float p2 = __expf(v2 - mn), p3 = __expf(v3 - mn);
        float ps = p0 + p1 + p2 + p3;
        ps += __shfl_xor(ps, 1);
        ps += __shfl_xor(ps, 2);
        ps += __shfl_xor(ps, 4);
        ps += __shfl_xor(ps, 8);
        lrow[r][j] = lrow[r][j] * corr + ps;
        o[r][0][j] *= corr; o[r][1][j] *= corr;
        o[r][2][j] *= corr; o[r][3][j] *= corr;
        int prow = r * 32 + g * 4 + j;          // note: row-block stride 32 rows? no:
        prow = r * 16 + g * 4 + j;
        Pw[prow * 68 +  0 + l15] = f2bf(p0);
        Pw[prow * 68 + 16 + l15] = f2bf(p1);
        Pw[prow * 68 + 32 + l15] = f2bf(p2);
        Pw[prow * 68 + 48 + l15] = f2bf(p3);
      }

    // PV: A = P (LDS, A-frag layout), B = V^T rows (registers, loaded at top)
    bf16x8 ap[2][2];
#pragma unroll
    for (int r = 0; r < 2; ++r)
#pragma unroll
      for (int ks = 0; ks < 2; ++ks)
        ap[r][ks] = lds_frag(Pw, r * 16 + l15, ks * 32 + g * 8, 68);
#pragma unroll
    for (int r = 0; r < 2; ++r)
#pragma unroll
      for (int n = 0; n < 4; ++n) {
        o[r][n] = MFMA16(ap[r][0], vf[n][0], o[r][n]);
        o[r][n] = MFMA16(ap[r][1], vf[n][1], o[r][n]);
      }

    // rotate prefetched K into place
#pragma unroll
    for (int n = 0; n < 4; ++n)
#pragma unroll
      for (int ks = 0; ks < 2; ++ks)
        kf[n][ks] = kn[n][ks];
  }

#pragma unroll
  for (int r = 0; r < 2; ++r)
#pragma unroll
    for (int j = 0; j < 4; ++j) {
      float inv = 1.0f / lrow[r][j];
      int row = q0 + r * 16 + g * 4 + j;
#pragma unroll
      for (int n = 0; n < 4; ++n) {
        int col = h * DH + n * 16 + l15;
        attnw[((size_t)(b * NSEQ + row)) * EMB + col] = o[r][n][j] * inv;
      }
    }
}

extern "C" void kernel_launch(void* const* d_in, const int* in_sizes, int n_in,
                              void* d_out, int out_size, void* d_ws, size_t ws_size,
                              hipStream_t stream) {
  const float* q  = (const float*)d_in[0];
  const float* Wq = (const float*)d_in[1];
  const float* bq = (const float*)d_in[2];
  const float* Wk = (const float*)d_in[3];
  const float* bk = (const float*)d_in[4];
  const float* Wv = (const float*)d_in[5];
  const float* bv = (const float*)d_in[6];
  const float* Wo = (const float*)d_in[7];
  const float* bo = (const float*)d_in[8];

  float* outp  = (float*)d_out;
  float* attnw = outp + MAT;          // second tuple element
  __bf16* ws   = (__bf16*)d_ws;       // Q | K | V^T  bf16, 3*MAT elements

  dim3 blk(256);
  qkv_kernel<<<dim3(8, 64, 3), blk, 0, stream>>>(q, Wq, bq, Wk, bk, Wv, bv, ws);
  flash_kernel<<<dim3(NSEQ / 128, NH, NB), blk, 0, stream>>>(ws, ws + MAT, ws + 2 * MAT, attnw);
  oproj_kernel<<<dim3(8, 64, 1), blk, 0, stream>>>(attnw, Wo, bo, outp);
}

// Round 3
// 404.561 us; speedup vs baseline: 1.6826x; 1.0470x over previous
//
#include <hip/hip_runtime.h>

typedef float  f32x4  __attribute__((ext_vector_type(4)));
typedef __bf16 bf16x4 __attribute__((ext_vector_type(4)));
typedef __bf16 bf16x8 __attribute__((ext_vector_type(8)));

#define MFMA16(a, b, c) __builtin_amdgcn_mfma_f32_16x16x32_bf16((a), (b), (c), 0, 0, 0)

constexpr int EMB  = 1024;
constexpr int NSEQ = 2048;
constexpr int NB   = 4;
constexpr int NH   = 16;
constexpr int DH   = 64;
constexpr size_t HSTRIDE = (size_t)NSEQ * DH;    // elements per head (Q/K/V)
constexpr size_t MAT     = (size_t)NB * NSEQ * EMB;  // 8388608

__device__ __forceinline__ __bf16 f2bf(float f) { return (__bf16)f; }

__device__ __forceinline__ bf16x8 lds_frag(const __bf16* base, int row, int koff, int stride) {
  const __bf16* p = base + row * stride + koff;
  bf16x4 lo = *reinterpret_cast<const bf16x4*>(p);
  bf16x4 hi = *reinterpret_cast<const bf16x4*>(p + 4);
  return __builtin_shufflevector(lo, hi, 0, 1, 2, 3, 4, 5, 6, 7);
}

// ---------------- GEMM core: C[m,n] = sum_k A[m,k] * W[n,k] + bias[n] ----------------
// MODE 0: fp32 out, row-major [M][EMB]
// MODE 1: bf16 out, layout [b][h][n][d]   (Q, K)
// MODE 2: bf16 out, layout [b][h][d][n]   (V transposed)
template <int MODE>
__device__ __forceinline__ void gemm_core(__bf16* Al, __bf16* Bl,
                                          const float* __restrict__ A,
                                          const float* __restrict__ W,
                                          const float* __restrict__ bias,
                                          float* __restrict__ outF,
                                          __bf16* __restrict__ outB) {
  const int t = threadIdx.x;
  const int lane = t & 63, wid = t >> 6;
  const int wr = wid >> 1, wc = wid & 1;
  const int m0 = blockIdx.y * 128, n0 = blockIdx.x * 128;
  const int l15 = lane & 15, g = lane >> 4;

  f32x4 acc[4][4];
#pragma unroll
  for (int i = 0; i < 4; ++i)
#pragma unroll
    for (int j = 0; j < 4; ++j) acc[i][j] = f32x4{0.f, 0.f, 0.f, 0.f};

#pragma unroll 1
  for (int k0 = 0; k0 < EMB; k0 += 32) {
#pragma unroll
    for (int jj = 0; jj < 4; ++jj) {
      int f = t + jj * 256;
      int row = f >> 3, kq = f & 7;            // 128 rows x 8 float4 = 128x32 tile
      f32x4 a4 = *reinterpret_cast<const f32x4*>(A + (size_t)(m0 + row) * EMB + k0 + kq * 4);
      f32x4 b4 = *reinterpret_cast<const f32x4*>(W + (size_t)(n0 + row) * EMB + k0 + kq * 4);
      bf16x4 av  = {f2bf(a4[0]), f2bf(a4[1]), f2bf(a4[2]), f2bf(a4[3])};
      bf16x4 bv4 = {f2bf(b4[0]), f2bf(b4[1]), f2bf(b4[2]), f2bf(b4[3])};
      *reinterpret_cast<bf16x4*>(Al + row * 40 + kq * 4) = av;   // stride 40 pads banks
      *reinterpret_cast<bf16x4*>(Bl + row * 40 + kq * 4) = bv4;
    }
    __syncthreads();
    bf16x8 af[4], bfr[4];
#pragma unroll
    for (int i = 0; i < 4; ++i) af[i]  = lds_frag(Al, wr * 64 + i * 16 + l15, g * 8, 40);
#pragma unroll
    for (int i = 0; i < 4; ++i) bfr[i] = lds_frag(Bl, wc * 64 + i * 16 + l15, g * 8, 40);
#pragma unroll
    for (int mi = 0; mi < 4; ++mi)
#pragma unroll
      for (int ni = 0; ni < 4; ++ni)
        acc[mi][ni] = MFMA16(af[mi], bfr[ni], acc[mi][ni]);
    __syncthreads();
  }

#pragma unroll
  for (int mi = 0; mi < 4; ++mi)
#pragma unroll
    for (int ni = 0; ni < 4; ++ni)
#pragma unroll
      for (int j = 0; j < 4; ++j) {
        int rg = m0 + wr * 64 + mi * 16 + g * 4 + j;   // C/D: row=(lane>>4)*4+reg
        int cg = n0 + wc * 64 + ni * 16 + l15;         //      col=lane&15
        float v = acc[mi][ni][j] + bias[cg];
        if constexpr (MODE == 0) {
          outF[(size_t)rg * EMB + cg] = v;
        } else {
          int bb = rg >> 11, r = rg & (NSEQ - 1);
          int hh = cg >> 6,  d = cg & (DH - 1);
          size_t hb = (size_t)(bb * NH + hh);
          if constexpr (MODE == 1)
            outB[(hb * NSEQ + r) * DH + d] = f2bf(v);
          else
            outB[(hb * DH + d) * NSEQ + r] = f2bf(v);
        }
      }
}

__global__ __launch_bounds__(256) void qkv_kernel(const float* __restrict__ x,
    const float* __restrict__ Wq, const float* __restrict__ bq,
    const float* __restrict__ Wk, const float* __restrict__ bk,
    const float* __restrict__ Wv, const float* __restrict__ bv,
    __bf16* __restrict__ ws) {
  __shared__ __align__(16) __bf16 smem[2 * 128 * 40];
  __bf16* Al = smem;
  __bf16* Bl = smem + 128 * 40;
  int z = blockIdx.z;
  if (z == 0)      gemm_core<1>(Al, Bl, x, Wq, bq, nullptr, ws);
  else if (z == 1) gemm_core<1>(Al, Bl, x, Wk, bk, nullptr, ws + MAT);
  else             gemm_core<2>(Al, Bl, x, Wv, bv, nullptr, ws + 2 * MAT);
}

__global__ __launch_bounds__(256) void oproj_kernel(const float* __restrict__ attnw,
    const float* __restrict__ Wo, const float* __restrict__ bo,
    float* __restrict__ outp) {
  __shared__ __align__(16) __bf16 smem[2 * 128 * 40];
  gemm_core<0>(smem, smem + 128 * 40, attnw, Wo, bo, outp, nullptr);
}

// ---------------- Flash attention ----------------
// Block = 128 q rows (4 waves x 32 rows). KV tiles of 64. No __syncthreads
// (per-wave-private P slice; intra-wave ds ordering via lgkmcnt).
// Softmax: defer-max (THR=8, T13) -> cross-lane max reduce only when the
// running max actually grows; row sums kept as per-lane partials and reduced
// ONCE at the end. Common-case tile has ZERO shuffles.
__global__ __launch_bounds__(256) void flash_kernel(const __bf16* __restrict__ Qb,
                                                    const __bf16* __restrict__ Kb,
                                                    const __bf16* __restrict__ Vtb,
                                                    float* __restrict__ attnw) {
  __shared__ __align__(16) __bf16 P[4 * 32 * 68];   // per-wave 32x68 P tile (bf16)
  const int t = threadIdx.x;
  const int lane = t & 63, w = t >> 6;
  const int l15 = lane & 15, g = lane >> 4;
  const int h = blockIdx.y, b = blockIdx.z;
  const size_t hoff = ((size_t)(b * NH + h)) * HSTRIDE;
  const __bf16* Qh = Qb + hoff;          // [2048][64]
  const __bf16* Kh = Kb + hoff;          // [2048][64]
  const __bf16* Vh = Vtb + hoff;         // [64][2048]  (transposed)
  const int q0 = blockIdx.x * 128 + w * 32;
  const float THR = 8.0f;

  // Q fragments hoisted to registers: 2 row-blocks x 2 k-splits
  bf16x8 aq[2][2];
#pragma unroll
  for (int r = 0; r < 2; ++r)
#pragma unroll
    for (int ks = 0; ks < 2; ++ks)
      aq[r][ks] = *reinterpret_cast<const bf16x8*>(
          Qh + (size_t)(q0 + r * 16 + l15) * DH + ks * 32 + g * 8);

  f32x4 o[2][4];
  float mrow[2][4], lsum[2][4];   // lsum = per-lane PARTIAL row sum
#pragma unroll
  for (int r = 0; r < 2; ++r)
#pragma unroll
    for (int i = 0; i < 4; ++i) {
      o[r][i] = f32x4{0.f, 0.f, 0.f, 0.f};
      mrow[r][i] = -1e30f;
      lsum[r][i] = 0.f;
    }

  __bf16* Pw = P + w * 32 * 68;

  // prologue: K fragments for tile 0
  bf16x8 kf[4][2];
#pragma unroll
  for (int n = 0; n < 4; ++n)
#pragma unroll
    for (int ks = 0; ks < 2; ++ks)
      kf[n][ks] = *reinterpret_cast<const bf16x8*>(
          Kh + (size_t)(n * 16 + l15) * DH + ks * 32 + g * 8);

#pragma unroll 1
  for (int kt = 0; kt < NSEQ; kt += 64) {
    // issue V loads for this tile (consumed by PV at the bottom)
    bf16x8 vf[4][2];
#pragma unroll
    for (int n = 0; n < 4; ++n)
#pragma unroll
      for (int ks = 0; ks < 2; ++ks)
        vf[n][ks] = *reinterpret_cast<const bf16x8*>(
            Vh + (size_t)(n * 16 + l15) * NSEQ + kt + ks * 32 + g * 8);

    // S = Q K^T  (2 row-blocks x 4 n-blocks, K=64)
    f32x4 s[2][4];
#pragma unroll
    for (int r = 0; r < 2; ++r)
#pragma unroll
      for (int n = 0; n < 4; ++n) {
        f32x4 z = f32x4{0.f, 0.f, 0.f, 0.f};
        z = MFMA16(aq[r][0], kf[n][0], z);
        z = MFMA16(aq[r][1], kf[n][1], z);
        s[r][n] = z;
      }

    // issue next tile's K loads (consumed next iteration)
    int ktn = (kt + 64 < NSEQ) ? kt + 64 : 0;   // last prefetch is dead
    bf16x8 kn[4][2];
#pragma unroll
    for (int n = 0; n < 4; ++n)
#pragma unroll
      for (int ks = 0; ks < 2; ++ks)
        kn[n][ks] = *reinterpret_cast<const bf16x8*>(
            Kh + (size_t)(ktn + n * 16 + l15) * DH + ks * 32 + g * 8);

    // online softmax with defer-max; rows live on 16-lane groups
#pragma unroll
    for (int r = 0; r < 2; ++r)
#pragma unroll
      for (int j = 0; j < 4; ++j) {
        float v0 = s[r][0][j] * 0.125f, v1 = s[r][1][j] * 0.125f;
        float v2 = s[r][2][j] * 0.125f, v3 = s[r][3][j] * 0.125f;
        float lm = fmaxf(fmaxf(v0, v1), fmaxf(v2, v3));
        if (__any(lm > mrow[r][j] + THR)) {
          // rare path: true cross-lane max update + rescale
          float mx = lm;
          mx = fmaxf(mx, __shfl_xor(mx, 1));
          mx = fmaxf(mx, __shfl_xor(mx, 2));
          mx = fmaxf(mx, __shfl_xor(mx, 4));
          mx = fmaxf(mx, __shfl_xor(mx, 8));
          float mn = fmaxf(mrow[r][j], mx);
          float corr = __expf(mrow[r][j] - mn);
          mrow[r][j] = mn;
          lsum[r][j] *= corr;
          o[r][0][j] *= corr; o[r][1][j] *= corr;
          o[r][2][j] *= corr; o[r][3][j] *= corr;
        }
        float m = mrow[r][j];
        float p0 = __expf(v0 - m), p1 = __expf(v1 - m);
        float p2 = __expf(v2 - m), p3 = __expf(v3 - m);
        lsum[r][j] += (p0 + p1) + (p2 + p3);
        int prow = r * 16 + g * 4 + j;
        Pw[prow * 68 +  0 + l15] = f2bf(p0);
        Pw[prow * 68 + 16 + l15] = f2bf(p1);
        Pw[prow * 68 + 32 + l15] = f2bf(p2);
        Pw[prow * 68 + 48 + l15] = f2bf(p3);
      }

    // PV: A = P (LDS, A-frag layout), B = V^T rows (registers, loaded at top)
    bf16x8 ap[2][2];
#pragma unroll
    for (int r = 0; r < 2; ++r)
#pragma unroll
      for (int ks = 0; ks < 2; ++ks)
        ap[r][ks] = lds_frag(Pw, r * 16 + l15, ks * 32 + g * 8, 68);
#pragma unroll
    for (int r = 0; r < 2; ++r)
#pragma unroll
      for (int n = 0; n < 4; ++n) {
        o[r][n] = MFMA16(ap[r][0], vf[n][0], o[r][n]);
        o[r][n] = MFMA16(ap[r][1], vf[n][1], o[r][n]);
      }

    // rotate prefetched K into place
#pragma unroll
    for (int n = 0; n < 4; ++n)
#pragma unroll
      for (int ks = 0; ks < 2; ++ks)
        kf[n][ks] = kn[n][ks];
  }

  // final: reduce per-lane partial sums across the 16 lanes of each row
#pragma unroll
  for (int r = 0; r < 2; ++r)
#pragma unroll
    for (int j = 0; j < 4; ++j) {
      float ps = lsum[r][j];
      ps += __shfl_xor(ps, 1);
      ps += __shfl_xor(ps, 2);
      ps += __shfl_xor(ps, 4);
      ps += __shfl_xor(ps, 8);
      float inv = 1.0f / ps;
      int row = q0 + r * 16 + g * 4 + j;
#pragma unroll
      for (int n = 0; n < 4; ++n) {
        int col = h * DH + n * 16 + l15;
        attnw[((size_t)(b * NSEQ + row)) * EMB + col] = o[r][n][j] * inv;
      }
    }
}

extern "C" void kernel_launch(void* const* d_in, const int* in_sizes, int n_in,
                              void* d_out, int out_size, void* d_ws, size_t ws_size,
                              hipStream_t stream) {
  const float* q  = (const float*)d_in[0];
  const float* Wq = (const float*)d_in[1];
  const float* bq = (const float*)d_in[2];
  const float* Wk = (const float*)d_in[3];
  const float* bk = (const float*)d_in[4];
  const float* Wv = (const float*)d_in[5];
  const float* bv = (const float*)d_in[6];
  const float* Wo = (const float*)d_in[7];
  const float* bo = (const float*)d_in[8];

  float* outp  = (float*)d_out;
  float* attnw = outp + MAT;          // second tuple element
  __bf16* ws   = (__bf16*)d_ws;       // Q | K | V^T  bf16, 3*MAT elements

  dim3 blk(256);
  qkv_kernel<<<dim3(8, 64, 3), blk, 0, stream>>>(q, Wq, bq, Wk, bk, Wv, bv, ws);
  flash_kernel<<<dim3(NSEQ / 128, NH, NB), blk, 0, stream>>>(ws, ws + MAT, ws + 2 * MAT, attnw);
  oproj_kernel<<<dim3(8, 64, 1), blk, 0, stream>>>(attnw, Wo, bo, outp);
}